// Round 5
// baseline (16.195 us; speedup 1.0000x reference)
//
#include <hip/hip_runtime.h>

// Problem constants: bs=2, V=4096, N=32, S=8, K=64 (S*K=512)
#define BS 2
#define V_DIM 4096
#define N_NBR 32
#define S_SUP 8
#define K_OUT 64
#define SK (S_SUP * K_OUT)
#define WAVES_PER_BLOCK 4

typedef float f32x2 __attribute__((ext_vector_type(2)));
typedef float f32x4 __attribute__((ext_vector_type(4)));

// __launch_bounds__(256, 8): 8 waves/SIMD min -> VGPR capped at 64 ->
// 32 waves/CU resident (vs 4 waves/SIMD at VGPR=124 before).
__global__ __launch_bounds__(WAVES_PER_BLOCK * 64, 8) void conv_surface_kernel(
    const int* __restrict__ nidx,     // (bs, V, N) int32
    const float* __restrict__ verts,  // (bs, V, 3) f32
    const float* __restrict__ dirs,   // (3, S*K)   f32
    float* __restrict__ out)          // (bs, V, K) f32
{
    const int lane = threadIdx.x & 63;
    const int wave = threadIdx.x >> 6;
    const int vi   = blockIdx.x * WAVES_PER_BLOCK + wave;   // in [0, BS*V)
    const int bbase = (vi >> 12) << 12;                     // batch base (V = 2^12)

    // Per-wave private LDS slice: [n] -> {ndx, ndy, ndz, pad}. No cross-wave
    // sharing => no __syncthreads (same-wave ds ordering via lgkmcnt).
    __shared__ __align__(16) float snd[WAVES_PER_BLOCK][N_NBR][4];

    // ---- critical chain head FIRST: idx load feeds the dependent gather ----
    int j = 0;
    if (lane < N_NBR) j = nidx[vi * N_NBR + lane];
    const float cx = verts[vi * 3 + 0];   // wave-uniform -> cache broadcast
    const float cy = verts[vi * 3 + 1];
    const float cz = verts[vi * 3 + 2];

    // ---- independent dirs loads issue while idx/center are in flight ----
    float a0[S_SUP], a1[S_SUP], a2[S_SUP];
#pragma unroll
    for (int s = 0; s < S_SUP; ++s) {
        const int m = s * K_OUT + lane;
        a0[s] = dirs[0 * SK + m];
        a1[s] = dirs[1 * SK + m];
        a2[s] = dirs[2 * SK + m];
    }

    // ---- dependent gather + normalize + LDS stage ----
    if (lane < N_NBR) {
        const float dx = verts[(bbase + j) * 3 + 0] - cx;
        const float dy = verts[(bbase + j) * 3 + 1] - cy;
        const float dz = verts[(bbase + j) * 3 + 2] - cz;
        // 1/max(sqrt(d2),1e-12) == rsqrt(max(d2,1e-24)); rsqrt(1e-24)*0 = 0.
        const float inv = __frsqrt_rn(fmaxf(dx * dx + dy * dy + dz * dz, 1e-24f));
        f32x4 q = {dx * inv, dy * inv, dz * inv, 0.0f};
        *reinterpret_cast<f32x4*>(&snd[wave][lane][0]) = q;   // ds_write_b128
    }

    // ---- normalize direction columns (VALU overlaps gather latency) ----
    f32x2 D0[S_SUP / 2], D1[S_SUP / 2], D2[S_SUP / 2];
#pragma unroll
    for (int p = 0; p < S_SUP / 2; ++p) {
        const int s0 = 2 * p, s1 = 2 * p + 1;
        const float i0 = __frsqrt_rn(fmaxf(a0[s0]*a0[s0] + a1[s0]*a1[s0] + a2[s0]*a2[s0], 1e-24f));
        const float i1 = __frsqrt_rn(fmaxf(a0[s1]*a0[s1] + a1[s1]*a1[s1] + a2[s1]*a2[s1], 1e-24f));
        D0[p] = (f32x2){a0[s0] * i0, a0[s1] * i1};
        D1[p] = (f32x2){a1[s0] * i0, a1[s1] * i1};
        D2[p] = (f32x2){a2[s0] * i0, a2[s1] * i1};
    }

    // relu + max over neighbors folds into max with 0 init.
    f32x2 th[S_SUP / 2];
#pragma unroll
    for (int p = 0; p < S_SUP / 2; ++p) th[p] = (f32x2){0.0f, 0.0f};

    // unroll 4: caps in-flight ds_read_b128 dest regs at 16 (VGPR <= 64 target)
#pragma unroll 4
    for (int n = 0; n < N_NBR; ++n) {
        const f32x4 q = *reinterpret_cast<const f32x4*>(&snd[wave][n][0]); // ds_read_b128, broadcast
        const f32x2 vx = (f32x2){q.x, q.x};
        const f32x2 vy = (f32x2){q.y, q.y};
        const f32x2 vz = (f32x2){q.z, q.z};
#pragma unroll
        for (int p = 0; p < S_SUP / 2; ++p) {
            f32x2 t = vx * D0[p];
            t = t + vy * D1[p];                           // v_pk_fma_f32
            t = t + vz * D2[p];
            th[p] = __builtin_elementwise_max(th[p], t);  // v_pk_max_f32
        }
    }

    // packed reduction: 3 pk adds + 1 scalar
    const f32x2 u = th[0] + th[1];
    const f32x2 w = th[2] + th[3];
    const f32x2 z = u + w;
    out[vi * K_OUT + lane] = z.x + z.y;   // coalesced 256B per wave
}

extern "C" void kernel_launch(void* const* d_in, const int* in_sizes, int n_in,
                              void* d_out, int out_size, void* d_ws, size_t ws_size,
                              hipStream_t stream) {
    const int*   nidx  = (const int*)d_in[0];
    const float* verts = (const float*)d_in[1];
    const float* dirs  = (const float*)d_in[2];
    float*       out   = (float*)d_out;

    const int total_v = BS * V_DIM;                       // 8192
    const int blocks  = total_v / WAVES_PER_BLOCK;        // 2048
    conv_surface_kernel<<<blocks, WAVES_PER_BLOCK * 64, 0, stream>>>(nidx, verts, dirs, out);
}

// Round 6
// 15.251 us; speedup vs baseline: 1.0618x; 1.0618x over previous
//
#include <hip/hip_runtime.h>

// Problem constants: bs=2, V=4096, N=32, S=8, K=64 (S*K=512)
#define BS 2
#define V_DIM 4096
#define N_NBR 32
#define S_SUP 8
#define K_OUT 64
#define SK (S_SUP * K_OUT)
#define WAVES_PER_BLOCK 4
#define VPW 2   // vertices per wave: lane-half h gathers vertex v0+h

typedef float f32x2 __attribute__((ext_vector_type(2)));
typedef float f32x4 __attribute__((ext_vector_type(4)));

__global__ __launch_bounds__(WAVES_PER_BLOCK * 64) void conv_surface_kernel(
    const int* __restrict__ nidx,     // (bs, V, N) int32
    const float* __restrict__ verts,  // (bs, V, 3) f32
    const float* __restrict__ dirs,   // (3, S*K)   f32
    float* __restrict__ out)          // (bs, V, K) f32
{
    const int lane = threadIdx.x & 63;
    const int wave = threadIdx.x >> 6;
    const int v0   = (blockIdx.x * WAVES_PER_BLOCK + wave) * VPW;

    // lane-half h handles vertex v0+h; ln = neighbor slot. All 64 lanes gather.
    const int h  = lane >> 5;
    const int ln = lane & 31;
    const int vg = v0 + h;
    const int bbase = (vg >> 12) << 12;    // batch base (V = 2^12)

    // Per-wave private LDS: [v][n] -> {ndx,ndy,ndz,pad}. No cross-wave sharing
    // => no __syncthreads (same-wave ds ordering via lgkmcnt).
    __shared__ __align__(16) float snd[WAVES_PER_BLOCK][VPW][N_NBR][4];

    // ---- critical chain head first ----
    const int j = nidx[vg * N_NBR + ln];
    const float cx = verts[vg * 3 + 0];    // uniform per half -> cache broadcast
    const float cy = verts[vg * 3 + 1];
    const float cz = verts[vg * 3 + 2];

    // ---- independent dirs loads issue while idx/center are in flight ----
    float a0[S_SUP], a1[S_SUP], a2[S_SUP];
#pragma unroll
    for (int s = 0; s < S_SUP; ++s) {
        const int m = s * K_OUT + lane;
        a0[s] = dirs[0 * SK + m];
        a1[s] = dirs[1 * SK + m];
        a2[s] = dirs[2 * SK + m];
    }

    // ---- dependent gather + normalize + LDS stage (all 64 lanes busy) ----
    {
        const float dx = verts[(bbase + j) * 3 + 0] - cx;
        const float dy = verts[(bbase + j) * 3 + 1] - cy;
        const float dz = verts[(bbase + j) * 3 + 2] - cz;
        // 1/max(sqrt(d2),1e-12) == rsqrt(max(d2,1e-24)); rsqrt(1e-24)*0 = 0.
        const float inv = __frsqrt_rn(fmaxf(dx * dx + dy * dy + dz * dz, 1e-24f));
        f32x4 q = {dx * inv, dy * inv, dz * inv, 0.0f};
        *reinterpret_cast<f32x4*>(&snd[wave][h][ln][0]) = q;   // ds_write_b128
    }

    // ---- normalize direction columns (VALU overlaps gather latency) ----
    f32x2 D0[S_SUP / 2], D1[S_SUP / 2], D2[S_SUP / 2];
#pragma unroll
    for (int p = 0; p < S_SUP / 2; ++p) {
        const int s0 = 2 * p, s1 = 2 * p + 1;
        const float i0 = __frsqrt_rn(fmaxf(a0[s0]*a0[s0] + a1[s0]*a1[s0] + a2[s0]*a2[s0], 1e-24f));
        const float i1 = __frsqrt_rn(fmaxf(a0[s1]*a0[s1] + a1[s1]*a1[s1] + a2[s1]*a2[s1], 1e-24f));
        D0[p] = (f32x2){a0[s0] * i0, a0[s1] * i1};
        D1[p] = (f32x2){a1[s0] * i0, a1[s1] * i1};
        D2[p] = (f32x2){a2[s0] * i0, a2[s1] * i1};
    }

    // ---- both vertices: packed relu/max inner loop (D registers shared) ----
#pragma unroll
    for (int v = 0; v < VPW; ++v) {
        f32x2 th[S_SUP / 2];
#pragma unroll
        for (int p = 0; p < S_SUP / 2; ++p) th[p] = (f32x2){0.0f, 0.0f};

#pragma unroll
        for (int n = 0; n < N_NBR; ++n) {
            const f32x4 q = *reinterpret_cast<const f32x4*>(&snd[wave][v][n][0]); // ds_read_b128 broadcast
            const f32x2 vx = (f32x2){q.x, q.x};
            const f32x2 vy = (f32x2){q.y, q.y};
            const f32x2 vz = (f32x2){q.z, q.z};
#pragma unroll
            for (int p = 0; p < S_SUP / 2; ++p) {
                f32x2 t = vx * D0[p];
                t = t + vy * D1[p];                           // v_pk_fma_f32
                t = t + vz * D2[p];
                th[p] = __builtin_elementwise_max(th[p], t);  // v_pk_max_f32
            }
        }

        const f32x2 u = th[0] + th[1];
        const f32x2 w = th[2] + th[3];
        const f32x2 z = u + w;
        out[(v0 + v) * K_OUT + lane] = z.x + z.y;   // coalesced 256B per wave
    }
}

extern "C" void kernel_launch(void* const* d_in, const int* in_sizes, int n_in,
                              void* d_out, int out_size, void* d_ws, size_t ws_size,
                              hipStream_t stream) {
    const int*   nidx  = (const int*)d_in[0];
    const float* verts = (const float*)d_in[1];
    const float* dirs  = (const float*)d_in[2];
    float*       out   = (float*)d_out;

    const int total_v = BS * V_DIM;                              // 8192
    const int blocks  = total_v / (WAVES_PER_BLOCK * VPW);       // 1024
    conv_surface_kernel<<<blocks, WAVES_PER_BLOCK * 64, 0, stream>>>(nidx, verts, dirs, out);
}